// Round 10
// baseline (319.950 us; speedup 1.0000x reference)
//
#include <hip/hip_runtime.h>
#include <math.h>

#define BATCH 2
#define SEQ   2048
#define DMODEL 1024
#define KDIM  1024
#define NH    16
#define HDIM  64
#define GRP   4
#define NKV   4   // NH / GRP
#define NSPLIT 4  // attention key-split

enum { M_PLAIN = 0, M_QKV = 1 };

// ln(10000)
#define LN_THETA 9.210340371976184f

typedef short bf8_t __attribute__((ext_vector_type(8)));
typedef float f4_t __attribute__((ext_vector_type(4)));
typedef unsigned short us4_t __attribute__((ext_vector_type(4)));
typedef unsigned short us8_t __attribute__((ext_vector_type(8)));
typedef _Float16 h_t;
typedef _Float16 h4_t __attribute__((ext_vector_type(4)));

// ws element offsets (bf16 units) -- Qb/Kb/Vb must stay contiguous in this order
#define QB_OFF 0
#define KB_OFF 4194304
#define VB_OFF (4194304 + 1048576)

__device__ __forceinline__ unsigned short f2bf(float f) {
  unsigned int u = __float_as_uint(f);
  u += 0x7fffu + ((u >> 16) & 1u);   // RNE
  return (unsigned short)(u >> 16);
}

__device__ __forceinline__ void gload_lds16(const void* g, void* l) {
  typedef __attribute__((address_space(1))) unsigned int gu32;
  typedef __attribute__((address_space(3))) unsigned int lu32;
  __builtin_amdgcn_global_load_lds((const gu32*)g, (lu32*)l, 16, 0, 0);
}

// ---- x fp32 -> bf16, same layout. grid*256*4 elements exactly.
__global__ __launch_bounds__(256) void conv_x(const float* __restrict__ in,
                                              unsigned short* __restrict__ out) {
  const int i = blockIdx.x * 256 + threadIdx.x;
  float4 v = ((const float4*)in)[i];
  us4_t o = {f2bf(v.x), f2bf(v.y), f2bf(v.z), f2bf(v.w)};
  ((us4_t*)out)[i] = o;
}

// ---- all 4 weight transposes in ONE launch (z routes). fp32 [K][N] -> bf16 [N][K].
__global__ __launch_bounds__(256) void convT_all(const float* __restrict__ W0,
                                                 const float* __restrict__ W1,
                                                 const float* __restrict__ W2,
                                                 const float* __restrict__ W3,
                                                 unsigned short* __restrict__ Wqkvt,
                                                 unsigned short* __restrict__ Wot) {
  const float* W; unsigned short* out; int N, rowoff;
  switch (blockIdx.z) {
    case 0: W = W0; out = Wqkvt; N = 1024; rowoff = 0;    break;
    case 1: W = W1; out = Wqkvt; N = 256;  rowoff = 1024; break;
    case 2: W = W2; out = Wqkvt; N = 256;  rowoff = 1280; break;
    default: W = W3; out = Wot;  N = 1024; rowoff = 0;    break;
  }
  const int n0 = blockIdx.x * 64;
  if (n0 >= N) return;
  __shared__ unsigned short T[64][72];
  const int t = threadIdx.x;
  const int k0 = blockIdx.y * 64;
  const int kr = t >> 4, n4 = (t & 15) * 4;
#pragma unroll
  for (int i = 0; i < 4; ++i) {
    const int k = kr + i * 16;
    float4 v = *(const float4*)&W[(size_t)(k0 + k) * N + n0 + n4];
    T[n4 + 0][k] = f2bf(v.x);
    T[n4 + 1][k] = f2bf(v.y);
    T[n4 + 2][k] = f2bf(v.z);
    T[n4 + 3][k] = f2bf(v.w);
  }
  __syncthreads();
#pragma unroll
  for (int i = 0; i < 2; ++i) {
    const int c = t + i * 256;
    const int n = c >> 3, kc = (c & 7) * 8;
    us8_t v = *(const us8_t*)&T[n][kc];
    *(us8_t*)&out[(size_t)(rowoff + n0 + n) * KDIM + k0 + kc] = v;
  }
}

// ---- bf16 MFMA GEMM: C[M x N] = A[M x 1024] @ Bt[N x 1024]^T.
// 64x128 tile (M x N), 4 waves in 2x2 (each 32x64), BK=64 as two BK=32
// panels with the verified XOR chunk swizzle (0 bank conflicts measured).
// Grid: (x = M/64 row-blocks [fast -> XCD-pinned A rows], y = N/128).
template <int MODE>
__global__ __launch_bounds__(256, 3) void gemm_bf16(const unsigned short* __restrict__ A,
                                                    const unsigned short* __restrict__ Bt,
                                                    void* __restrict__ Cdst_, int N) {
  __shared__ __align__(16) unsigned short As[64 * 64];    //  8 KB: 2 panels of 64x32
  __shared__ __align__(16) unsigned short Bs[128 * 64];   // 16 KB: 2 panels of 128x32

  const int tid = threadIdx.x;
  const int lane = tid & 63, quad = lane >> 4, l16 = lane & 15;
  const int w = tid >> 6, wm = w >> 1, wn = w & 1;
  const int row0 = blockIdx.x * 64, col0 = blockIdx.y * 128;

  const int m0 = tid >> 2;
  const int kc0 = (tid & 3) ^ ((m0 >> 1) & 3);
  const unsigned short* Ag0 = A + (size_t)(row0 + m0) * KDIM + kc0 * 8;
  const unsigned short* Bg0 = Bt + (size_t)(col0 + m0) * KDIM + kc0 * 8;
  unsigned short* Al0 = &As[tid * 8];
  unsigned short* Bl0 = &Bs[tid * 8];

  int aoff[2][2], boff[4][2];
#pragma unroll
  for (int mi = 0; mi < 2; ++mi) {
    const int am = wm * 32 + mi * 16 + l16;
    const int sw = quad ^ ((am >> 1) & 3);
#pragma unroll
    for (int kh = 0; kh < 2; ++kh)
      aoff[mi][kh] = kh * 2048 + (((am << 2) | sw) << 3);
  }
#pragma unroll
  for (int ni = 0; ni < 4; ++ni) {
    const int bn = wn * 64 + ni * 16 + l16;
    const int sw = quad ^ ((bn >> 1) & 3);
#pragma unroll
    for (int kh = 0; kh < 2; ++kh)
      boff[ni][kh] = kh * 4096 + (((bn << 2) | sw) << 3);
  }

  f4_t acc[2][4];
#pragma unroll
  for (int mi = 0; mi < 2; ++mi)
#pragma unroll
    for (int ni = 0; ni < 4; ++ni) acc[mi][ni] = (f4_t){0.f, 0.f, 0.f, 0.f};

  for (int kb = 0; kb < KDIM; kb += 64) {
    __syncthreads();
    gload_lds16(Ag0 + kb,       Al0);
    gload_lds16(Ag0 + kb + 32,  Al0 + 2048);
    gload_lds16(Bg0 + kb,                     Bl0);
    gload_lds16(Bg0 + (size_t)64 * KDIM + kb, Bl0 + 2048);
    gload_lds16(Bg0 + kb + 32,                     Bl0 + 4096);
    gload_lds16(Bg0 + (size_t)64 * KDIM + kb + 32, Bl0 + 6144);
    __syncthreads();

    bf8_t af[2][2], bfr[4][2];
#pragma unroll
    for (int mi = 0; mi < 2; ++mi)
#pragma unroll
      for (int kh = 0; kh < 2; ++kh) af[mi][kh] = *(const bf8_t*)&As[aoff[mi][kh]];
#pragma unroll
    for (int ni = 0; ni < 4; ++ni)
#pragma unroll
      for (int kh = 0; kh < 2; ++kh) bfr[ni][kh] = *(const bf8_t*)&Bs[boff[ni][kh]];
#pragma unroll
    for (int kh = 0; kh < 2; ++kh)
#pragma unroll
      for (int mi = 0; mi < 2; ++mi)
#pragma unroll
        for (int ni = 0; ni < 4; ++ni)
          acc[mi][ni] = __builtin_amdgcn_mfma_f32_16x16x32_bf16(af[mi][kh], bfr[ni][kh], acc[mi][ni], 0, 0, 0);
  }

  if constexpr (MODE == M_PLAIN) {
    float* out = (float*)Cdst_;
#pragma unroll
    for (int mi = 0; mi < 2; ++mi) {
      const int rowb = row0 + wm * 32 + mi * 16 + quad * 4;
#pragma unroll
      for (int ni = 0; ni < 4; ++ni) {
        const int n = col0 + wn * 64 + ni * 16 + l16;
#pragma unroll
        for (int r = 0; r < 4; ++r)
          out[(size_t)(rowb + r) * N + n] = acc[mi][ni][r];
      }
    }
  } else {  // M_QKV
    unsigned short* Qb = (unsigned short*)Cdst_;
    unsigned short* Kb = Qb + (KB_OFF - QB_OFF);
    unsigned short* Vb = Qb + (VB_OFF - QB_OFF);
#pragma unroll
    for (int ni = 0; ni < 4; ++ni) {
      const int nb = col0 + wn * 64 + ni * 16;   // wave-uniform region selector
      const int n = nb + l16;
      if (nb < 1024) {  // Q + full-D RoPE, scale 1/32 folded
        const float inv = expf(-(float)(2 * (n >> 1)) * (LN_THETA / (float)DMODEL));
        const float sgn = (n & 1) ? 1.f : -1.f;
        const int h = n >> 6, d = n & 63;
#pragma unroll
        for (int mi = 0; mi < 2; ++mi) {
          const int rowb = row0 + wm * 32 + mi * 16 + quad * 4;
#pragma unroll
          for (int r = 0; r < 4; ++r) {
            const int row = rowb + r;
            const int bb = row >> 11, s = row & (SEQ - 1);
            const float v = acc[mi][ni][r];
            const float p = __shfl_xor(v, 1);
            float sn, cs;
            sincosf((float)s * inv, &sn, &cs);
            const float res = (v * cs + sgn * p * sn) * 0.03125f;
            Qb[((size_t)(bb * NH + h) * SEQ + s) * HDIM + d] = f2bf(res);
          }
        }
      } else if (nb < 1280) {  // K + per-head RoPE (freqs [0,32))
        const int nk = n - 1024;
        const int hkv = nk >> 6, d = nk & 63;
        const float inv = expf(-(float)(2 * (d >> 1)) * (LN_THETA / (float)DMODEL));
        const float sgn = (nk & 1) ? 1.f : -1.f;
#pragma unroll
        for (int mi = 0; mi < 2; ++mi) {
          const int rowb = row0 + wm * 32 + mi * 16 + quad * 4;
#pragma unroll
          for (int r = 0; r < 4; ++r) {
            const int row = rowb + r;
            const int bb = row >> 11, s = row & (SEQ - 1);
            const float v = acc[mi][ni][r];
            const float p = __shfl_xor(v, 1);
            float sn, cs;
            sincosf((float)s * inv, &sn, &cs);
            const float res = v * cs + sgn * p * sn;
            Kb[((size_t)(bb * NKV + hkv) * SEQ + s) * HDIM + d] = f2bf(res);
          }
        }
      } else {  // V, transposed [B][NKV][HDIM][pkey]: keys PERMUTED within each
                // 64-tile: key (cb,quad_k,r) -> pos (cb>>1)*32+quad_k*8+(cb&1)*4+r
                // (matches attn's register-packed PV k-axis; bit-shuffle below)
        const int nv = n - 1280;
        const int hkv = nv >> 6, d = nv & 63;
#pragma unroll
        for (int mi = 0; mi < 2; ++mi) {
          const int s0 = row0 + wm * 32 + mi * 16 + quad * 4;
          const int bb = s0 >> 11, sl = s0 & (SEQ - 1);
          const int st = sl & 63;   // low 2 bits are 0
          const int ps = (sl & ~63) | (st & 0x20) | ((st & 0x0C) << 1) | ((st & 0x10) >> 2);
          us4_t stv = {f2bf(acc[mi][ni][0]), f2bf(acc[mi][ni][1]),
                       f2bf(acc[mi][ni][2]), f2bf(acc[mi][ni][3])};
          *(us4_t*)&Vb[((size_t)(bb * NKV + hkv) * HDIM + d) * SEQ + ps] = stv;
        }
      }
    }
  }
}

// ---- MFMA flash attention v6. Key-split x NSPLIT, 4 waves x 32q, 64-key
// tiles. LDS uses the GEMM-verified 64-B-row panel layout (two 64x32 panels
// per tile, slot swizzle quad^((row>>1)&3)) for BOTH K (d-half panels) and
// V (key-half panels) -> all fragment reads are the bank-proven b128 form.
// V global layout is key-PERMUTED so one b128 = the 8 keys a lane's PV
// A-fragment packs (registers, no P LDS round-trip). Fixed softmax max m=0;
// partials (f16 O, f32 L) merge by pure summation.
__global__ __launch_bounds__(256, 6) void attn_fwd(const unsigned short* __restrict__ Q,
                                                   const unsigned short* __restrict__ K,
                                                   const unsigned short* __restrict__ V,
                                                   h_t* __restrict__ Opart,
                                                   float* __restrict__ Lpart) {
  __shared__ __align__(16) unsigned short Kt[4096];  // 2 panels [key][d-half], 8 KB
  __shared__ __align__(16) unsigned short Vt[4096];  // 2 panels [d][pkey-half], 8 KB

  const int b = blockIdx.x >> 4;
  const int h = blockIdx.x & (NH - 1);
  const int hkv = h >> 2;
  const int q0 = blockIdx.y * 128;
  const int sp = blockIdx.z;
  const int tid = threadIdx.x;
  const int w = tid >> 6;
  const int lane = tid & 63;
  const int quad = lane >> 4;
  const int l16 = lane & 15;

  const unsigned short* Qg = Q + ((size_t)(b * NH + h) * SEQ + q0 + w * 32) * HDIM;
  const unsigned short* Kg = K + (size_t)(b * NKV + hkv) * SEQ * HDIM;
  const unsigned short* Vg = V + (size_t)(b * NKV + hkv) * HDIM * SEQ;

  // Q as B-fragments: lane(n=l16 -> q, quad) holds Q[q][d=half*32+quad*8+j]
  bf8_t qb[2][2];
#pragma unroll
  for (int g = 0; g < 2; ++g)
#pragma unroll
    for (int half = 0; half < 2; ++half)
      qb[g][half] = *(const bf8_t*)(Qg + (size_t)(g * 16 + l16) * HDIM + half * 32 + quad * 8);

  f4_t accO[2][4];
#pragma unroll
  for (int g = 0; g < 2; ++g)
#pragma unroll
    for (int d = 0; d < 4; ++d) accO[g][d] = (f4_t){0.f, 0.f, 0.f, 0.f};
  float accLs[2] = {0.f, 0.f};

  // fragment slot swizzle (row = cb*16+l16 or db*16+l16; (row>>1)&3 = (l16>>1)&3)
  const int sw8 = (quad ^ ((l16 >> 1) & 3)) << 3;   // element offset of 16B slot

  // staging: thread t -> row t>>2, slot t&3, global chunk (t&3)^((row>>1)&3)
  const int skey = tid >> 2;
  const int gc = ((tid & 3) ^ ((tid >> 3) & 3)) << 3;
  const unsigned short* KgA = Kg + (size_t)skey * HDIM + gc;
  const unsigned short* VgA = Vg + (size_t)skey * SEQ + gc;

  const int kbeg = sp * (SEQ / NSPLIT);
  const int kend = kbeg + SEQ / NSPLIT;
  for (int k0 = kbeg; k0 < kend; k0 += 64) {
    __syncthreads();
    gload_lds16(KgA + (size_t)k0 * HDIM,      &Kt[tid * 8]);         // d 0..31
    gload_lds16(KgA + (size_t)k0 * HDIM + 32, &Kt[tid * 8 + 2048]);  // d 32..63
    gload_lds16(VgA + k0,      &Vt[tid * 8]);                        // pkey 0..31
    gload_lds16(VgA + k0 + 32, &Vt[tid * 8 + 2048]);                 // pkey 32..63
    __syncthreads();

    // S^T = K Q^T per 16-key block; P = exp(S^T) packed straight into
    // PV A-fragments (permuted k-axis; bitwise round-half-up + v_perm)
    union { bf8_t bf; unsigned int dw[4]; } pa[2][2];
#pragma unroll
    for (int cb = 0; cb < 4; ++cb) {
      const int koff = (cb * 16 + l16) * 32 + sw8;
      bf8_t kf0 = *(const bf8_t*)&Kt[koff];
      bf8_t kf1 = *(const bf8_t*)&Kt[koff + 2048];
#pragma unroll
      for (int g = 0; g < 2; ++g) {
        f4_t s = (f4_t){0.f, 0.f, 0.f, 0.f};
        s = __builtin_amdgcn_mfma_f32_16x16x32_bf16(kf0, qb[g][0], s, 0, 0, 0);
        s = __builtin_amdgcn_mfma_f32_16x16x32_bf16(kf1, qb[g][1], s, 0, 0, 0);
        const float p0 = __expf(s[0]), p1 = __expf(s[1]);
        const float p2 = __expf(s[2]), p3 = __expf(s[3]);
        accLs[g] += (p0 + p1) + (p2 + p3);
        pa[g][cb >> 1].dw[(cb & 1) * 2 + 0] =
            __builtin_amdgcn_perm(__float_as_uint(p1) + 0x8000u,
                                  __float_as_uint(p0) + 0x8000u, 0x07060302u);
        pa[g][cb >> 1].dw[(cb & 1) * 2 + 1] =
            __builtin_amdgcn_perm(__float_as_uint(p3) + 0x8000u,
                                  __float_as_uint(p2) + 0x8000u, 0x07060302u);
      }
    }

    // O += P V ; V B-frag = one b128 (permuted global key order matches pa)
#pragma unroll
    for (int db = 0; db < 4; ++db) {
      const int voff = (db * 16 + l16) * 32 + sw8;
      bf8_t vf0 = *(const bf8_t*)&Vt[voff];
      bf8_t vf1 = *(const bf8_t*)&Vt[voff + 2048];
#pragma unroll
      for (int g = 0; g < 2; ++g) {
        accO[g][db] = __builtin_amdgcn_mfma_f32_16x16x32_bf16(pa[g][0].bf, vf0, accO[g][db], 0, 0, 0);
        accO[g][db] = __builtin_amdgcn_mfma_f32_16x16x32_bf16(pa[g][1].bf, vf1, accO[g][db], 0, 0, 0);
      }
    }
  }

  // L: per-lane partials cover keys {quad*4+r} for q=l16 -> reduce across quads
#pragma unroll
  for (int g = 0; g < 2; ++g) {
    accLs[g] += __shfl_xor(accLs[g], 16);
    accLs[g] += __shfl_xor(accLs[g], 32);
  }

  // write unnormalized partials (O in f16: |o| <~ 40, rel err 5e-4 -> safe)
  h_t* Osp = Opart + (size_t)sp * BATCH * SEQ * NH * HDIM;
  float* Lsp = Lpart + (size_t)sp * BATCH * SEQ * NH;
#pragma unroll
  for (int g = 0; g < 2; ++g)
#pragma unroll
    for (int r = 0; r < 4; ++r) {
      const int q = q0 + w * 32 + g * 16 + quad * 4 + r;
      const size_t rowi = ((size_t)b * SEQ + q) * NH + h;
      h_t* op = Osp + rowi * HDIM;
#pragma unroll
      for (int db = 0; db < 4; ++db)
        op[db * 16 + l16] = (h_t)accO[g][db][r];
    }
  if (quad == 0) {
#pragma unroll
    for (int g = 0; g < 2; ++g) {
      const int q = q0 + w * 32 + g * 16 + l16;
      Lsp[((size_t)b * SEQ + q) * NH + h] = accLs[g];
    }
  }
}

// ---- merge key-split partials: Ow[g][j] = (sum_sp O[sp][g][j]) / (sum_sp L[sp][g])
__global__ __launch_bounds__(256) void attn_merge(const h_t* __restrict__ Opart,
                                                  const float* __restrict__ Lpart,
                                                  unsigned short* __restrict__ Ow) {
  const int idx = blockIdx.x * 256 + threadIdx.x;   // over nq*16
  const int g = idx >> 4, j = (idx & 15) * 4;
  const size_t nq = (size_t)BATCH * SEQ * NH;
  float L = 0.f;
  float4 acc = make_float4(0.f, 0.f, 0.f, 0.f);
#pragma unroll
  for (int u = 0; u < NSPLIT; ++u) {
    L += Lpart[u * nq + g];
    h4_t o = *(const h4_t*)&Opart[((size_t)u * nq + g) * HDIM + j];
    acc.x += (float)o[0]; acc.y += (float)o[1];
    acc.z += (float)o[2]; acc.w += (float)o[3];
  }
  const float il = 1.0f / L;
  us4_t o = {f2bf(acc.x * il), f2bf(acc.y * il), f2bf(acc.z * il), f2bf(acc.w * il)};
  *(us4_t*)&Ow[(size_t)g * HDIM + j] = o;
}

extern "C" void kernel_launch(void* const* d_in, const int* in_sizes, int n_in,
                              void* d_out, int out_size, void* d_ws, size_t ws_size,
                              hipStream_t stream) {
  (void)in_sizes; (void)n_in; (void)out_size; (void)ws_size;
  const float* x  = (const float*)d_in[0];
  const float* Wq = (const float*)d_in[1];
  const float* Wk = (const float*)d_in[2];
  const float* Wv = (const float*)d_in[3];
  const float* Wo = (const float*)d_in[4];
  float* out = (float*)d_out;

  // ws layout. bf16 region (~34.6 MB) + f16 O partials (33.5 MB) + L (1 MB)
  // = ~69 MB, within the proven >=76.5 MB budget.
  unsigned short* Qb    = (unsigned short*)d_ws;          // 4194304
  unsigned short* Kb    = Qb + 4194304;                   // 1048576
  unsigned short* Vb    = Kb + 1048576;                   // 1048576
  unsigned short* xb    = Vb + 1048576;                   // 4194304
  unsigned short* Owb   = xb + 4194304;                   // 4194304
  unsigned short* Wqkvt = Owb + 4194304;                  // 1572864 (Q|K|V rows)
  unsigned short* Wot   = Wqkvt + 1572864;                // 1048576
  h_t* Opart = (h_t*)(Wot + 1048576);                     // NSPLIT * 4194304 f16
  float* Lpart = (float*)(Opart + (size_t)NSPLIT * 4194304);  // NSPLIT*65536 f32

  dim3 blk(256);
  conv_x<<<dim3(4096), blk, 0, stream>>>(x, xb);
  convT_all<<<dim3(16, 16, 4), blk, 0, stream>>>(Wq, Wk, Wv, Wo, Wqkvt, Wot);

  gemm_bf16<M_QKV><<<dim3(64, 12), blk, 0, stream>>>(xb, Wqkvt, Qb, 1536);
  attn_fwd<<<dim3(BATCH * NH, SEQ / 128, NSPLIT), blk, 0, stream>>>(Qb, Kb, Vb, Opart, Lpart);
  attn_merge<<<dim3(4096), blk, 0, stream>>>(Opart, Lpart, Owb);
  gemm_bf16<M_PLAIN><<<dim3(64, 8), blk, 0, stream>>>(Owb, Wot, out, DMODEL);
}

// Round 11
// 172.252 us; speedup vs baseline: 1.8575x; 1.8575x over previous
//
#include <hip/hip_runtime.h>
#include <math.h>

#define BATCH 2
#define SEQ   2048
#define DMODEL 1024
#define KDIM  1024
#define NH    16
#define HDIM  64
#define GRP   4
#define NKV   4   // NH / GRP
#define NSPLIT 4  // attention key-split

enum { M_PLAIN = 0, M_QKV = 1 };

// ln(10000)
#define LN_THETA 9.210340371976184f

typedef short bf8_t __attribute__((ext_vector_type(8)));
typedef float f4_t __attribute__((ext_vector_type(4)));
typedef unsigned short us4_t __attribute__((ext_vector_type(4)));
typedef unsigned short us8_t __attribute__((ext_vector_type(8)));
typedef _Float16 h_t;
typedef _Float16 h4_t __attribute__((ext_vector_type(4)));

// ws element offsets (bf16 units) -- Qb/Kb/Vb must stay contiguous in this order
#define QB_OFF 0
#define KB_OFF 4194304
#define VB_OFF (4194304 + 1048576)

__device__ __forceinline__ unsigned short f2bf(float f) {
  unsigned int u = __float_as_uint(f);
  u += 0x7fffu + ((u >> 16) & 1u);   // RNE
  return (unsigned short)(u >> 16);
}

__device__ __forceinline__ void gload_lds16(const void* g, void* l) {
  typedef __attribute__((address_space(1))) unsigned int gu32;
  typedef __attribute__((address_space(3))) unsigned int lu32;
  __builtin_amdgcn_global_load_lds((const gu32*)g, (lu32*)l, 16, 0, 0);
}

// ---- x fp32 -> bf16, same layout. grid*256*4 elements exactly.
__global__ __launch_bounds__(256) void conv_x(const float* __restrict__ in,
                                              unsigned short* __restrict__ out) {
  const int i = blockIdx.x * 256 + threadIdx.x;
  float4 v = ((const float4*)in)[i];
  us4_t o = {f2bf(v.x), f2bf(v.y), f2bf(v.z), f2bf(v.w)};
  ((us4_t*)out)[i] = o;
}

// ---- all 4 weight transposes in ONE launch (z routes). fp32 [K][N] -> bf16 [N][K].
__global__ __launch_bounds__(256) void convT_all(const float* __restrict__ W0,
                                                 const float* __restrict__ W1,
                                                 const float* __restrict__ W2,
                                                 const float* __restrict__ W3,
                                                 unsigned short* __restrict__ Wqkvt,
                                                 unsigned short* __restrict__ Wot) {
  const float* W; unsigned short* out; int N, rowoff;
  switch (blockIdx.z) {
    case 0: W = W0; out = Wqkvt; N = 1024; rowoff = 0;    break;
    case 1: W = W1; out = Wqkvt; N = 256;  rowoff = 1024; break;
    case 2: W = W2; out = Wqkvt; N = 256;  rowoff = 1280; break;
    default: W = W3; out = Wot;  N = 1024; rowoff = 0;    break;
  }
  const int n0 = blockIdx.x * 64;
  if (n0 >= N) return;
  __shared__ unsigned short T[64][72];
  const int t = threadIdx.x;
  const int k0 = blockIdx.y * 64;
  const int kr = t >> 4, n4 = (t & 15) * 4;
#pragma unroll
  for (int i = 0; i < 4; ++i) {
    const int k = kr + i * 16;
    float4 v = *(const float4*)&W[(size_t)(k0 + k) * N + n0 + n4];
    T[n4 + 0][k] = f2bf(v.x);
    T[n4 + 1][k] = f2bf(v.y);
    T[n4 + 2][k] = f2bf(v.z);
    T[n4 + 3][k] = f2bf(v.w);
  }
  __syncthreads();
#pragma unroll
  for (int i = 0; i < 2; ++i) {
    const int c = t + i * 256;
    const int n = c >> 3, kc = (c & 7) * 8;
    us8_t v = *(const us8_t*)&T[n][kc];
    *(us8_t*)&out[(size_t)(rowoff + n0 + n) * KDIM + k0 + kc] = v;
  }
}

// ---- bf16 MFMA GEMM: C[M x N] = A[M x 1024] @ Bt[N x 1024]^T.
// 64x128 tile (M x N), 4 waves in 2x2 (each 32x64), BK=64 as two BK=32
// panels with the verified XOR chunk swizzle (0 bank conflicts measured).
// Grid: (x = M/64 row-blocks [fast -> XCD-pinned A rows], y = N/128).
template <int MODE>
__global__ __launch_bounds__(256, 3) void gemm_bf16(const unsigned short* __restrict__ A,
                                                    const unsigned short* __restrict__ Bt,
                                                    void* __restrict__ Cdst_, int N) {
  __shared__ __align__(16) unsigned short As[64 * 64];    //  8 KB: 2 panels of 64x32
  __shared__ __align__(16) unsigned short Bs[128 * 64];   // 16 KB: 2 panels of 128x32

  const int tid = threadIdx.x;
  const int lane = tid & 63, quad = lane >> 4, l16 = lane & 15;
  const int w = tid >> 6, wm = w >> 1, wn = w & 1;
  const int row0 = blockIdx.x * 64, col0 = blockIdx.y * 128;

  const int m0 = tid >> 2;
  const int kc0 = (tid & 3) ^ ((m0 >> 1) & 3);
  const unsigned short* Ag0 = A + (size_t)(row0 + m0) * KDIM + kc0 * 8;
  const unsigned short* Bg0 = Bt + (size_t)(col0 + m0) * KDIM + kc0 * 8;
  unsigned short* Al0 = &As[tid * 8];
  unsigned short* Bl0 = &Bs[tid * 8];

  int aoff[2][2], boff[4][2];
#pragma unroll
  for (int mi = 0; mi < 2; ++mi) {
    const int am = wm * 32 + mi * 16 + l16;
    const int sw = quad ^ ((am >> 1) & 3);
#pragma unroll
    for (int kh = 0; kh < 2; ++kh)
      aoff[mi][kh] = kh * 2048 + (((am << 2) | sw) << 3);
  }
#pragma unroll
  for (int ni = 0; ni < 4; ++ni) {
    const int bn = wn * 64 + ni * 16 + l16;
    const int sw = quad ^ ((bn >> 1) & 3);
#pragma unroll
    for (int kh = 0; kh < 2; ++kh)
      boff[ni][kh] = kh * 4096 + (((bn << 2) | sw) << 3);
  }

  f4_t acc[2][4];
#pragma unroll
  for (int mi = 0; mi < 2; ++mi)
#pragma unroll
    for (int ni = 0; ni < 4; ++ni) acc[mi][ni] = (f4_t){0.f, 0.f, 0.f, 0.f};

  for (int kb = 0; kb < KDIM; kb += 64) {
    __syncthreads();
    gload_lds16(Ag0 + kb,       Al0);
    gload_lds16(Ag0 + kb + 32,  Al0 + 2048);
    gload_lds16(Bg0 + kb,                     Bl0);
    gload_lds16(Bg0 + (size_t)64 * KDIM + kb, Bl0 + 2048);
    gload_lds16(Bg0 + kb + 32,                     Bl0 + 4096);
    gload_lds16(Bg0 + (size_t)64 * KDIM + kb + 32, Bl0 + 6144);
    __syncthreads();

    bf8_t af[2][2], bfr[4][2];
#pragma unroll
    for (int mi = 0; mi < 2; ++mi)
#pragma unroll
      for (int kh = 0; kh < 2; ++kh) af[mi][kh] = *(const bf8_t*)&As[aoff[mi][kh]];
#pragma unroll
    for (int ni = 0; ni < 4; ++ni)
#pragma unroll
      for (int kh = 0; kh < 2; ++kh) bfr[ni][kh] = *(const bf8_t*)&Bs[boff[ni][kh]];
#pragma unroll
    for (int kh = 0; kh < 2; ++kh)
#pragma unroll
      for (int mi = 0; mi < 2; ++mi)
#pragma unroll
        for (int ni = 0; ni < 4; ++ni)
          acc[mi][ni] = __builtin_amdgcn_mfma_f32_16x16x32_bf16(af[mi][kh], bfr[ni][kh], acc[mi][ni], 0, 0, 0);
  }

  if constexpr (MODE == M_PLAIN) {
    float* out = (float*)Cdst_;
#pragma unroll
    for (int mi = 0; mi < 2; ++mi) {
      const int rowb = row0 + wm * 32 + mi * 16 + quad * 4;
#pragma unroll
      for (int ni = 0; ni < 4; ++ni) {
        const int n = col0 + wn * 64 + ni * 16 + l16;
#pragma unroll
        for (int r = 0; r < 4; ++r)
          out[(size_t)(rowb + r) * N + n] = acc[mi][ni][r];
      }
    }
  } else {  // M_QKV
    unsigned short* Qb = (unsigned short*)Cdst_;
    unsigned short* Kb = Qb + (KB_OFF - QB_OFF);
    unsigned short* Vb = Qb + (VB_OFF - QB_OFF);
#pragma unroll
    for (int ni = 0; ni < 4; ++ni) {
      const int nb = col0 + wn * 64 + ni * 16;   // wave-uniform region selector
      const int n = nb + l16;
      if (nb < 1024) {  // Q + full-D RoPE, scale 1/32 folded
        const float inv = expf(-(float)(2 * (n >> 1)) * (LN_THETA / (float)DMODEL));
        const float sgn = (n & 1) ? 1.f : -1.f;
        const int h = n >> 6, d = n & 63;
#pragma unroll
        for (int mi = 0; mi < 2; ++mi) {
          const int rowb = row0 + wm * 32 + mi * 16 + quad * 4;
#pragma unroll
          for (int r = 0; r < 4; ++r) {
            const int row = rowb + r;
            const int bb = row >> 11, s = row & (SEQ - 1);
            const float v = acc[mi][ni][r];
            const float p = __shfl_xor(v, 1);
            float sn, cs;
            sincosf((float)s * inv, &sn, &cs);
            const float res = (v * cs + sgn * p * sn) * 0.03125f;
            Qb[((size_t)(bb * NH + h) * SEQ + s) * HDIM + d] = f2bf(res);
          }
        }
      } else if (nb < 1280) {  // K + per-head RoPE (freqs [0,32))
        const int nk = n - 1024;
        const int hkv = nk >> 6, d = nk & 63;
        const float inv = expf(-(float)(2 * (d >> 1)) * (LN_THETA / (float)DMODEL));
        const float sgn = (nk & 1) ? 1.f : -1.f;
#pragma unroll
        for (int mi = 0; mi < 2; ++mi) {
          const int rowb = row0 + wm * 32 + mi * 16 + quad * 4;
#pragma unroll
          for (int r = 0; r < 4; ++r) {
            const int row = rowb + r;
            const int bb = row >> 11, s = row & (SEQ - 1);
            const float v = acc[mi][ni][r];
            const float p = __shfl_xor(v, 1);
            float sn, cs;
            sincosf((float)s * inv, &sn, &cs);
            const float res = v * cs + sgn * p * sn;
            Kb[((size_t)(bb * NKV + hkv) * SEQ + s) * HDIM + d] = f2bf(res);
          }
        }
      } else {  // V, transposed [B][NKV][HDIM][pkey]: keys PERMUTED within each
                // 64-tile: key (cb,quad_k,r) -> pos (cb>>1)*32+quad_k*8+(cb&1)*4+r
                // (matches attn's register-packed PV k-axis; bit-shuffle below)
        const int nv = n - 1280;
        const int hkv = nv >> 6, d = nv & 63;
#pragma unroll
        for (int mi = 0; mi < 2; ++mi) {
          const int s0 = row0 + wm * 32 + mi * 16 + quad * 4;
          const int bb = s0 >> 11, sl = s0 & (SEQ - 1);
          const int st = sl & 63;   // low 2 bits are 0
          const int ps = (sl & ~63) | (st & 0x20) | ((st & 0x0C) << 1) | ((st & 0x10) >> 2);
          us4_t stv = {f2bf(acc[mi][ni][0]), f2bf(acc[mi][ni][1]),
                       f2bf(acc[mi][ni][2]), f2bf(acc[mi][ni][3])};
          *(us4_t*)&Vb[((size_t)(bb * NKV + hkv) * HDIM + d) * SEQ + ps] = stv;
        }
      }
    }
  }
}

// ---- MFMA flash attention v6b. Key-split x NSPLIT, 4 waves x 32q, 64-key
// tiles. LDS uses the GEMM-verified 64-B-row panel layout (two 64x32 panels
// per tile, slot swizzle quad^((row>>1)&3)) for BOTH K (d-half panels) and
// V (key-half panels) -> all fragment reads are the bank-proven b128 form
// (R10 measured SQ_LDS_BANK_CONFLICT = 0). V global layout is key-PERMUTED
// so one b128 = the 8 keys a lane's PV A-fragment packs (registers, no P
// LDS round-trip). Fixed softmax max m=0; partials (f16 O, f32 L) merge by
// pure summation.
// launch_bounds (256,4): R10's (256,6) forced VGPR=40 -> spill storm
// (FETCH 326MB/WRITE 483MB of scratch traffic, 4x dur). Keep 4.
__global__ __launch_bounds__(256, 4) void attn_fwd(const unsigned short* __restrict__ Q,
                                                   const unsigned short* __restrict__ K,
                                                   const unsigned short* __restrict__ V,
                                                   h_t* __restrict__ Opart,
                                                   float* __restrict__ Lpart) {
  __shared__ __align__(16) unsigned short Kt[4096];  // 2 panels [key][d-half], 8 KB
  __shared__ __align__(16) unsigned short Vt[4096];  // 2 panels [d][pkey-half], 8 KB

  const int b = blockIdx.x >> 4;
  const int h = blockIdx.x & (NH - 1);
  const int hkv = h >> 2;
  const int q0 = blockIdx.y * 128;
  const int sp = blockIdx.z;
  const int tid = threadIdx.x;
  const int w = tid >> 6;
  const int lane = tid & 63;
  const int quad = lane >> 4;
  const int l16 = lane & 15;

  const unsigned short* Qg = Q + ((size_t)(b * NH + h) * SEQ + q0 + w * 32) * HDIM;
  const unsigned short* Kg = K + (size_t)(b * NKV + hkv) * SEQ * HDIM;
  const unsigned short* Vg = V + (size_t)(b * NKV + hkv) * HDIM * SEQ;

  // Q as B-fragments: lane(n=l16 -> q, quad) holds Q[q][d=half*32+quad*8+j]
  bf8_t qb[2][2];
#pragma unroll
  for (int g = 0; g < 2; ++g)
#pragma unroll
    for (int half = 0; half < 2; ++half)
      qb[g][half] = *(const bf8_t*)(Qg + (size_t)(g * 16 + l16) * HDIM + half * 32 + quad * 8);

  f4_t accO[2][4];
#pragma unroll
  for (int g = 0; g < 2; ++g)
#pragma unroll
    for (int d = 0; d < 4; ++d) accO[g][d] = (f4_t){0.f, 0.f, 0.f, 0.f};
  float accLs[2] = {0.f, 0.f};

  // fragment slot swizzle (row = cb*16+l16 or db*16+l16; (row>>1)&3 = (l16>>1)&3)
  const int sw8 = (quad ^ ((l16 >> 1) & 3)) << 3;   // element offset of 16B slot

  // staging: thread t -> row t>>2, slot t&3, global chunk (t&3)^((row>>1)&3)
  const int skey = tid >> 2;
  const int gc = ((tid & 3) ^ ((tid >> 3) & 3)) << 3;
  const unsigned short* KgA = Kg + (size_t)skey * HDIM + gc;
  const unsigned short* VgA = Vg + (size_t)skey * SEQ + gc;

  const int kbeg = sp * (SEQ / NSPLIT);
  const int kend = kbeg + SEQ / NSPLIT;
  for (int k0 = kbeg; k0 < kend; k0 += 64) {
    __syncthreads();
    gload_lds16(KgA + (size_t)k0 * HDIM,      &Kt[tid * 8]);         // d 0..31
    gload_lds16(KgA + (size_t)k0 * HDIM + 32, &Kt[tid * 8 + 2048]);  // d 32..63
    gload_lds16(VgA + k0,      &Vt[tid * 8]);                        // pkey 0..31
    gload_lds16(VgA + k0 + 32, &Vt[tid * 8 + 2048]);                 // pkey 32..63
    __syncthreads();

    // S^T = K Q^T per 16-key block; P = exp(S^T) packed straight into
    // PV A-fragments (permuted k-axis; bitwise round-half-up + v_perm)
    union { bf8_t bf; unsigned int dw[4]; } pa[2][2];
#pragma unroll
    for (int cb = 0; cb < 4; ++cb) {
      const int koff = (cb * 16 + l16) * 32 + sw8;
      bf8_t kf0 = *(const bf8_t*)&Kt[koff];
      bf8_t kf1 = *(const bf8_t*)&Kt[koff + 2048];
#pragma unroll
      for (int g = 0; g < 2; ++g) {
        f4_t s = (f4_t){0.f, 0.f, 0.f, 0.f};
        s = __builtin_amdgcn_mfma_f32_16x16x32_bf16(kf0, qb[g][0], s, 0, 0, 0);
        s = __builtin_amdgcn_mfma_f32_16x16x32_bf16(kf1, qb[g][1], s, 0, 0, 0);
        const float p0 = __expf(s[0]), p1 = __expf(s[1]);
        const float p2 = __expf(s[2]), p3 = __expf(s[3]);
        accLs[g] += (p0 + p1) + (p2 + p3);
        pa[g][cb >> 1].dw[(cb & 1) * 2 + 0] =
            __builtin_amdgcn_perm(__float_as_uint(p1) + 0x8000u,
                                  __float_as_uint(p0) + 0x8000u, 0x07060302u);
        pa[g][cb >> 1].dw[(cb & 1) * 2 + 1] =
            __builtin_amdgcn_perm(__float_as_uint(p3) + 0x8000u,
                                  __float_as_uint(p2) + 0x8000u, 0x07060302u);
      }
    }

    // O += P V ; V B-frag = one b128 (permuted global key order matches pa)
#pragma unroll
    for (int db = 0; db < 4; ++db) {
      const int voff = (db * 16 + l16) * 32 + sw8;
      bf8_t vf0 = *(const bf8_t*)&Vt[voff];
      bf8_t vf1 = *(const bf8_t*)&Vt[voff + 2048];
#pragma unroll
      for (int g = 0; g < 2; ++g) {
        accO[g][db] = __builtin_amdgcn_mfma_f32_16x16x32_bf16(pa[g][0].bf, vf0, accO[g][db], 0, 0, 0);
        accO[g][db] = __builtin_amdgcn_mfma_f32_16x16x32_bf16(pa[g][1].bf, vf1, accO[g][db], 0, 0, 0);
      }
    }
  }

  // L: per-lane partials cover keys {quad*4+r} for q=l16 -> reduce across quads
#pragma unroll
  for (int g = 0; g < 2; ++g) {
    accLs[g] += __shfl_xor(accLs[g], 16);
    accLs[g] += __shfl_xor(accLs[g], 32);
  }

  // write unnormalized partials (O in f16: |o| <~ 40, rel err 5e-4 -> safe)
  h_t* Osp = Opart + (size_t)sp * BATCH * SEQ * NH * HDIM;
  float* Lsp = Lpart + (size_t)sp * BATCH * SEQ * NH;
#pragma unroll
  for (int g = 0; g < 2; ++g)
#pragma unroll
    for (int r = 0; r < 4; ++r) {
      const int q = q0 + w * 32 + g * 16 + quad * 4 + r;
      const size_t rowi = ((size_t)b * SEQ + q) * NH + h;
      h_t* op = Osp + rowi * HDIM;
#pragma unroll
      for (int db = 0; db < 4; ++db)
        op[db * 16 + l16] = (h_t)accO[g][db][r];
    }
  if (quad == 0) {
#pragma unroll
    for (int g = 0; g < 2; ++g) {
      const int q = q0 + w * 32 + g * 16 + l16;
      Lsp[((size_t)b * SEQ + q) * NH + h] = accLs[g];
    }
  }
}

// ---- merge key-split partials: Ow[g][j] = (sum_sp O[sp][g][j]) / (sum_sp L[sp][g])
__global__ __launch_bounds__(256) void attn_merge(const h_t* __restrict__ Opart,
                                                  const float* __restrict__ Lpart,
                                                  unsigned short* __restrict__ Ow) {
  const int idx = blockIdx.x * 256 + threadIdx.x;   // over nq*16
  const int g = idx >> 4, j = (idx & 15) * 4;
  const size_t nq = (size_t)BATCH * SEQ * NH;
  float L = 0.f;
  float4 acc = make_float4(0.f, 0.f, 0.f, 0.f);
#pragma unroll
  for (int u = 0; u < NSPLIT; ++u) {
    L += Lpart[u * nq + g];
    h4_t o = *(const h4_t*)&Opart[((size_t)u * nq + g) * HDIM + j];
    acc.x += (float)o[0]; acc.y += (float)o[1];
    acc.z += (float)o[2]; acc.w += (float)o[3];
  }
  const float il = 1.0f / L;
  us4_t o = {f2bf(acc.x * il), f2bf(acc.y * il), f2bf(acc.z * il), f2bf(acc.w * il)};
  *(us4_t*)&Ow[(size_t)g * HDIM + j] = o;
}

extern "C" void kernel_launch(void* const* d_in, const int* in_sizes, int n_in,
                              void* d_out, int out_size, void* d_ws, size_t ws_size,
                              hipStream_t stream) {
  (void)in_sizes; (void)n_in; (void)out_size; (void)ws_size;
  const float* x  = (const float*)d_in[0];
  const float* Wq = (const float*)d_in[1];
  const float* Wk = (const float*)d_in[2];
  const float* Wv = (const float*)d_in[3];
  const float* Wo = (const float*)d_in[4];
  float* out = (float*)d_out;

  // ws layout. bf16 region (~34.6 MB) + f16 O partials (33.5 MB) + L (1 MB)
  // = ~69 MB, within the proven >=76.5 MB budget.
  unsigned short* Qb    = (unsigned short*)d_ws;          // 4194304
  unsigned short* Kb    = Qb + 4194304;                   // 1048576
  unsigned short* Vb    = Kb + 1048576;                   // 1048576
  unsigned short* xb    = Vb + 1048576;                   // 4194304
  unsigned short* Owb   = xb + 4194304;                   // 4194304
  unsigned short* Wqkvt = Owb + 4194304;                  // 1572864 (Q|K|V rows)
  unsigned short* Wot   = Wqkvt + 1572864;                // 1048576
  h_t* Opart = (h_t*)(Wot + 1048576);                     // NSPLIT * 4194304 f16
  float* Lpart = (float*)(Opart + (size_t)NSPLIT * 4194304);  // NSPLIT*65536 f32

  dim3 blk(256);
  conv_x<<<dim3(4096), blk, 0, stream>>>(x, xb);
  convT_all<<<dim3(16, 16, 4), blk, 0, stream>>>(Wq, Wk, Wv, Wo, Wqkvt, Wot);

  gemm_bf16<M_QKV><<<dim3(64, 12), blk, 0, stream>>>(xb, Wqkvt, Qb, 1536);
  attn_fwd<<<dim3(BATCH * NH, SEQ / 128, NSPLIT), blk, 0, stream>>>(Qb, Kb, Vb, Opart, Lpart);
  attn_merge<<<dim3(4096), blk, 0, stream>>>(Opart, Lpart, Owb);
  gemm_bf16<M_PLAIN><<<dim3(64, 8), blk, 0, stream>>>(Owb, Wot, out, DMODEL);
}